// Round 12
// baseline (5333.915 us; speedup 1.0000x reference)
//
#include <hip/hip_runtime.h>

#define HIDDEN 4096
#define NKV 8
#define NH 32
#define HD 128
#define BATCH 2
#define SEQ 4096
#define ROWS (BATCH*SEQ)   // 8192

typedef short bf16x8 __attribute__((ext_vector_type(8)));
typedef float f32x4 __attribute__((ext_vector_type(4)));

static __device__ __forceinline__ float bf2f(unsigned short u) {
    union { unsigned int i; float f; } c; c.i = ((unsigned int)u) << 16; return c.f;
}
static __device__ __forceinline__ unsigned short f2bf(float x) {
    union { float f; unsigned int i; } c; c.f = x;
    unsigned int r = c.i + 0x7fffu + ((c.i >> 16) & 1u);
    return (unsigned short)(r >> 16);
}

static __device__ __forceinline__ void gl2lds16(const void* g, void* l) {
    __builtin_amdgcn_global_load_lds(
        (const __attribute__((address_space(1))) unsigned int*)g,
        (__attribute__((address_space(3))) unsigned int*)l, 16, 0, 0);
}

#define WGBAR() __builtin_amdgcn_s_barrier()
#define VMW(n) asm volatile("s_waitcnt vmcnt(" #n ")" ::: "memory")
#define LGKM(n) asm volatile("s_waitcnt lgkmcnt(" #n ")" ::: "memory")
#define SCHED_FENCE() __builtin_amdgcn_sched_barrier(0)

// ---------------------------------------------------------------- casts
__global__ __launch_bounds__(256)
void cast_kernel(const float* __restrict__ in, unsigned short* __restrict__ out, int n4) {
    int idx = blockIdx.x * blockDim.x + threadIdx.x;
    int stride = gridDim.x * blockDim.x;
    for (int i = idx; i < n4; i += stride) {
        float4 f = ((const float4*)in)[i];
        ushort4 o;
        o.x = f2bf(f.x); o.y = f2bf(f.y); o.z = f2bf(f.z); o.w = f2bf(f.w);
        ((ushort4*)out)[i] = o;
    }
}

// ---------------------------------------------------------------- 256x256 GEMM, BK=32, 2 bufs x 32KB (64KB LDS -> 2 blocks/CU).
// Distance-1, drain-all-before-barrier (round-9/10 proven-safe schedule):
// stage tile t+1 at top of tile t; per-wave counted lgkmcnt pipelines the 12
// ds_reads under the 4 MFMA clusters; VMW(0)+barrier at end publishes the
// staged buffer workgroup-wide (zero vmem in flight across barriers).
// Inter-block TLP (2 blocks/CU) hides the drain/barrier serialization that
// capped the 1-block/CU variants at ~46% MfmaUtil.
// LDS panel layout: [r%128][128B], inner = ((r/128)<<6 | k*2) ^ ((r&7)<<4).
// MODE 0: f32 out, +bias0
// MODE 1: bf16 out, phi(x + bias0)          (Q projection)
// MODE 2: bf16 out, col<1024: phi(x+bias0[col]) else x+bias1[col-1024]  (fused KV)
template<int MODE>
__global__ __launch_bounds__(512, 4)
void gemm256(const unsigned short* __restrict__ A, int lda,
             const unsigned short* __restrict__ B, int ldb,
             const float* __restrict__ bias0, const float* __restrict__ bias1,
             void* __restrict__ Cout, int M, int N, int K)
{
    __shared__ __align__(16) unsigned char sm[65536];   // 2 x (A 16KB + B 16KB)

    const int tid = threadIdx.x;
    const int wid = tid >> 6, lane = tid & 63;
    const int wr = wid >> 2, wc = wid & 3;           // wave grid 2M x 4N
    const int lr = lane & 15, kg = lane >> 4;
    const int swz = (lane & 7) << 4;

    // XCD-aware block swizzle (nwg % 8 == 0 for all launches here)
    int nbx = N >> 8;
    int nwg = nbx * (M >> 8);
    int cpx = nwg >> 3;
    int bid = (int)blockIdx.x;
    int wg = (bid & 7) * cpx + (bid >> 3);
    int bx = wg % nbx, by = wg / nbx;
    int rowBase = by << 8, colBase = bx << 8;

    // staging source offsets: invert layout at linear dest o = i*8192+tid*16
    size_t sA[2], sB[2];
#pragma unroll
    for (int i = 0; i < 2; ++i) {
        int o = i * 8192 + tid * 16;
        int rm = o >> 7;
        int inner = (o & 127) ^ ((rm & 7) << 4);
        int half = inner >> 6;
        int ke = (inner & 63) >> 1;
        sA[i] = (size_t)(rowBase + half * 128 + rm) * lda + ke;
        sB[i] = (size_t)(colBase + half * 128 + rm) * ldb + ke;
    }
    const int ldsW = wid * 1024;

    auto STAGE = [&](int nb, size_t ko) {
        gl2lds16(A + sA[0] + ko, sm + nb + 0 * 8192 + ldsW);
        gl2lds16(A + sA[1] + ko, sm + nb + 1 * 8192 + ldsW);
        gl2lds16(B + sB[0] + ko, sm + nb + 16384 + 0 * 8192 + ldsW);
        gl2lds16(B + sB[1] + ko, sm + nb + 16384 + 1 * 8192 + ldsW);
    };

    const int aRd = (lr << 7) + ((((wr << 6) | (kg << 4))) ^ swz);
    const int bRd = 16384 + ((((wc & 1) * 64 + lr)) << 7)
                  + (((((wc >> 1) << 6) | (kg << 4))) ^ swz);

    auto RA = [&](int cb, int mp) -> bf16x8 {
        return *(const bf16x8*)(sm + cb + aRd + mp * 2048);
    };
    auto RB = [&](int cb, int n) -> bf16x8 {
        return *(const bf16x8*)(sm + cb + bRd + n * 2048);
    };

    f32x4 acc[8][4] = {};
    bf16x8 bfr[4];

    auto MF2 = [&](bf16x8 x0, bf16x8 x1, int m0, int m1) {
        SCHED_FENCE();                     // rule 18: pin MFMAs below the wait
        __builtin_amdgcn_s_setprio(1);
#pragma unroll
        for (int n = 0; n < 4; ++n) {
            acc[m0][n] = __builtin_amdgcn_mfma_f32_16x16x32_bf16(x0, bfr[n], acc[m0][n], 0, 0, 0);
            acc[m1][n] = __builtin_amdgcn_mfma_f32_16x16x32_bf16(x1, bfr[n], acc[m1][n], 0, 0, 0);
        }
        __builtin_amdgcn_s_setprio(0);
        SCHED_FENCE();
    };

    // per-tile compute on buffer cb: 12 ds_reads pipelined under 4 MFMA clusters
    auto TILE = [&](int cb) {
        // G1 (6 reads): all B + A mp0,1
        bfr[0] = RB(cb, 0); bfr[1] = RB(cb, 1); bfr[2] = RB(cb, 2); bfr[3] = RB(cb, 3);
        bf16x8 a0 = RA(cb, 0), a1 = RA(cb, 1);
        SCHED_FENCE();
        // G2 (2): A mp2,3
        bf16x8 a2 = RA(cb, 2), a3 = RA(cb, 3);
        SCHED_FENCE();
        LGKM(2);                // G1 done (G2 in flight)
        MF2(a0, a1, 0, 1);
        // G3 (2): A mp4,5
        a0 = RA(cb, 4); a1 = RA(cb, 5);
        SCHED_FENCE();
        LGKM(2);                // G2 done
        MF2(a2, a3, 2, 3);
        // G4 (2): A mp6,7
        a2 = RA(cb, 6); a3 = RA(cb, 7);
        SCHED_FENCE();
        LGKM(2);                // G3 done
        MF2(a0, a1, 4, 5);
        LGKM(0);                // G4 done
        MF2(a2, a3, 6, 7);
    };

    const int NT = K >> 5;      // K-tiles of 32

    // prologue: stage tile 0, publish
    SCHED_FENCE();
    STAGE(0, 0);
    SCHED_FENCE();
    VMW(0);
    WGBAR();
    SCHED_FENCE();

    int cur = 0;
    for (int t = 0; t < NT; ++t) {
        const int cb = cur << 15;
        if (t + 1 < NT) {
            SCHED_FENCE();
            STAGE((cur ^ 1) << 15, (size_t)(t + 1) * 32);   // tile t+1
            SCHED_FENCE();
        }
        TILE(cb);
        if (t + 1 < NT) {
            VMW(0);             // drain own stages (cover = this tile's compute)
            WGBAR();            // publish workgroup-wide; next tile reads it
            SCHED_FENCE();
        }
        cur ^= 1;
    }

    // ---- C write
    int r0 = rowBase + wr * 128 + kg * 4;
    int c0 = colBase + wc * 64 + lr;
#pragma unroll
    for (int n = 0; n < 4; ++n) {
        int col = c0 + n * 16;
        float bv;
        if (MODE == 2) bv = (col < 1024) ? bias0[col] : bias1[col - 1024];
        else           bv = bias0[col];
#pragma unroll
        for (int m = 0; m < 8; ++m) {
            int row = r0 + m * 16;
#pragma unroll
            for (int r = 0; r < 4; ++r) {
                float v = acc[m][n][r] + bv;
                if (MODE == 1) v = (v > 0.f) ? v + 1.f : __expf(v);
                if (MODE == 2 && col < 1024) v = (v > 0.f) ? v + 1.f : __expf(v);
                if (MODE == 0) ((float*)Cout)[(size_t)(row + r) * N + col] = v;
                else ((unsigned short*)Cout)[(size_t)(row + r) * N + col] = f2bf(v);
            }
        }
    }
}

// ---------------------------------------------------------------- kv partial: kv[c][d] += v[l,c]*k[l,d] over an L-chunk
__global__ __launch_bounds__(256)
void kv_partial(const unsigned short* __restrict__ Kb, const unsigned short* __restrict__ Vb,
                int ld, float* __restrict__ kvp, float* __restrict__ ksp)
{
    int chunk = blockIdx.x;   // 0..31 (128 rows each)
    int g = blockIdx.y;       // 0..15 = b*8+hkv
    int b = g >> 3, hkv = g & 7;
    __shared__ float kl[32][128];
    __shared__ float vl[32][128];
    int tid = threadIdx.x;
    int c0 = (tid >> 4) * 8, d0 = (tid & 15) * 8;
    float acc[8][8] = {};
    float ksacc = 0.0f;
    size_t rowBase = (size_t)b * SEQ + (size_t)chunk * 128;

    for (int sch = 0; sch < 4; ++sch) {
        __syncthreads();
        for (int t = tid; t < 512; t += 256) {
            int l = t >> 4, col = (t & 15) * 8;
            size_t off = (rowBase + sch * 32 + l) * ld + hkv * HD + col;
            uint4 kr = *(const uint4*)(Kb + off);
            uint4 vr = *(const uint4*)(Vb + off);
            unsigned int ku[4] = {kr.x, kr.y, kr.z, kr.w};
            unsigned int vu[4] = {vr.x, vr.y, vr.z, vr.w};
#pragma unroll
            for (int q = 0; q < 4; ++q) {
                kl[l][col + q * 2]     = bf2f((unsigned short)(ku[q] & 0xffff));
                kl[l][col + q * 2 + 1] = bf2f((unsigned short)(ku[q] >> 16));
                vl[l][col + q * 2]     = bf2f((unsigned short)(vu[q] & 0xffff));
                vl[l][col + q * 2 + 1] = bf2f((unsigned short)(vu[q] >> 16));
            }
        }
        __syncthreads();
        for (int l = 0; l < 32; ++l) {
            float vv[8], kk[8];
#pragma unroll
            for (int x = 0; x < 8; ++x) { vv[x] = vl[l][c0 + x]; kk[x] = kl[l][d0 + x]; }
#pragma unroll
            for (int x = 0; x < 8; ++x)
#pragma unroll
                for (int y = 0; y < 8; ++y)
                    acc[x][y] += vv[x] * kk[y];
        }
        if (tid < 128) {
            for (int l = 0; l < 32; ++l) ksacc += kl[l][tid];
        }
    }
    float* out = kvp + ((size_t)g * 32 + chunk) * (HD * HD);
#pragma unroll
    for (int x = 0; x < 8; ++x)
#pragma unroll
        for (int y = 0; y < 8; ++y)
            out[(c0 + x) * HD + d0 + y] = acc[x][y];
    if (tid < 128) ksp[((size_t)g * 32 + chunk) * HD + tid] = ksacc;
}

// ---------------------------------------------------------------- reduce partials -> kv_bf16, ksum
__global__ __launch_bounds__(256)
void kv_reduce(const float* __restrict__ kvp, const float* __restrict__ ksp,
               unsigned short* __restrict__ kvb, float* __restrict__ ksum)
{
    int slice = blockIdx.x;  // 0..15
    int g = blockIdx.y;      // 0..15
    int tid = threadIdx.x;
    int e = slice * 1024 + tid * 4;
    float4 s = {0.f, 0.f, 0.f, 0.f};
    for (int ch = 0; ch < 32; ++ch) {
        float4 p = *(const float4*)(kvp + ((size_t)g * 32 + ch) * (HD * HD) + e);
        s.x += p.x; s.y += p.y; s.z += p.z; s.w += p.w;
    }
    ushort4 o;
    o.x = f2bf(s.x); o.y = f2bf(s.y); o.z = f2bf(s.z); o.w = f2bf(s.w);
    *(ushort4*)(kvb + (size_t)g * HD * HD + e) = o;
    if (slice == 0 && tid < 128) {
        float ss = 0.f;
        for (int ch = 0; ch < 32; ++ch) ss += ksp[((size_t)g * 32 + ch) * HD + tid];
        ksum[g * HD + tid] = ss;
    }
}

// ---------------------------------------------------------------- attn GEMM: per (row-tile, head): C = q @ kv^T, /(ksum+eps), bf16 out
__global__ __launch_bounds__(256)
void attn_gemm(const unsigned short* __restrict__ Q,
               const unsigned short* __restrict__ KV,
               const float* __restrict__ KS,
               unsigned short* __restrict__ Out)
{
    const int BK = 32;
    __shared__ unsigned short As[128 * BK];
    __shared__ unsigned short Bs[128 * BK];

    int rt = blockIdx.x;   // 0..63
    int h  = blockIdx.y;   // 0..31
    int g = (rt >> 5) * NKV + (h >> 2);
    int rowBase = rt << 7;

    const unsigned short* A = Q + (size_t)h * HD;           // lda = HIDDEN
    const unsigned short* B = KV + (size_t)g * HD * HD;     // ldb = HD
    const float* ks = KS + g * HD;

    int tid = threadIdx.x;
    int wave = tid >> 6, lane = tid & 63;
    int wr = wave >> 1, wc = wave & 1;

    f32x4 acc[4][4] = {};

    int sr = lane >> 2;
    int sc = (lane & 3) * 8;

    const unsigned short* Aw = A + (size_t)(rowBase + wave * 32 + sr) * HIDDEN + sc;
    const unsigned short* Bw = B + (size_t)(wave * 32 + sr) * HD + sc;
    unsigned short* Asw = As + wave * 32 * BK;
    unsigned short* Bsw = Bs + wave * 32 * BK;

    int arow = (wr * 64 + (lane & 15)) * BK + (lane >> 4) * 8;
    int brow = (wc * 64 + (lane & 15)) * BK + (lane >> 4) * 8;

    for (int kt = 0; kt < HD; kt += BK) {
        gl2lds16(Aw + kt, Asw);
        gl2lds16(Aw + kt + (size_t)16 * HIDDEN, Asw + 16 * BK);
        gl2lds16(Bw + kt, Bsw);
        gl2lds16(Bw + kt + (size_t)16 * HD, Bsw + 16 * BK);
        __syncthreads();
        bf16x8 af[4], bfr[4];
#pragma unroll
        for (int i = 0; i < 4; ++i) af[i] = *(const bf16x8*)&As[arow + i * 16 * BK];
#pragma unroll
        for (int j = 0; j < 4; ++j) bfr[j] = *(const bf16x8*)&Bs[brow + j * 16 * BK];
#pragma unroll
        for (int i = 0; i < 4; ++i)
#pragma unroll
            for (int j = 0; j < 4; ++j)
                acc[i][j] = __builtin_amdgcn_mfma_f32_16x16x32_bf16(af[i], bfr[j], acc[i][j], 0, 0, 0);
        __syncthreads();
    }

    int r0 = rowBase + wr * 64 + ((lane >> 4) << 2);
    int c0 = wc * 64 + (lane & 15);
#pragma unroll
    for (int j = 0; j < 4; ++j) {
        int col = c0 + j * 16;
        float inv = 1.0f / (ks[col] + 1e-10f);
#pragma unroll
        for (int i = 0; i < 4; ++i) {
            int row = r0 + i * 16;
#pragma unroll
            for (int r = 0; r < 4; ++r) {
                float v = acc[i][j][r] * inv;
                Out[(size_t)(row + r) * HIDDEN + h * HD + col] = f2bf(v);
            }
        }
    }
}

// ---------------------------------------------------------------- launch
extern "C" void kernel_launch(void* const* d_in, const int* in_sizes, int n_in,
                              void* d_out, int out_size, void* d_ws, size_t ws_size,
                              hipStream_t stream)
{
    const float* hs = (const float*)d_in[0];
    const float* Wq = (const float*)d_in[1];
    const float* bq = (const float*)d_in[2];
    const float* Wk = (const float*)d_in[3];
    const float* bk = (const float*)d_in[4];
    const float* Wv = (const float*)d_in[5];
    const float* bv = (const float*)d_in[6];
    const float* Wo = (const float*)d_in[7];
    const float* bo = (const float*)d_in[8];

    char* ws = (char*)d_ws;
    size_t off = 0;
    auto alloc = [&](size_t bytes) -> char* {
        char* p = ws + off;
        off += (bytes + 255) & ~(size_t)255;
        return p;
    };

    unsigned short* hs_b  = (unsigned short*)alloc((size_t)ROWS * HIDDEN * 2);    // 67 MB (reused by attn out)
    unsigned short* Wq_b  = (unsigned short*)alloc((size_t)HIDDEN * HIDDEN * 2);  // 33.5 MB (reused by kvp)
    unsigned short* Wkv_b = (unsigned short*)alloc((size_t)2048 * HIDDEN * 2);    // 16.8 MB (Wk rows 0..1023, Wv rows 1024..2047)
    unsigned short* Wo_b  = (unsigned short*)alloc((size_t)HIDDEN * HIDDEN * 2);  // 33.5 MB
    unsigned short* kvout = (unsigned short*)alloc((size_t)ROWS * 2048 * 2);      // 33.5 MB [row][K(1024)|V(1024)]
    float* ksp   = (float*)alloc((size_t)16 * 32 * HD * 4);
    unsigned short* kvb = (unsigned short*)alloc((size_t)16 * HD * HD * 2);
    float* ksum  = (float*)alloc((size_t)16 * HD * 4);

    // aliases (lifetime-disjoint):
    float* kvp = (float*)Wq_b;                    // Wq dead after Q GEMM
    unsigned short* attn_b = hs_b;                // hs dead after KV GEMM
    unsigned short* q_b = (unsigned short*)d_out; // front 67 MB of d_out, dead before final GEMM writes

    (void)in_sizes; (void)n_in; (void)out_size; (void)ws_size;

    auto cast = [&](const float* in, unsigned short* out, size_t n) {
        int n4 = (int)(n / 4);
        int blocks = (n4 + 255) / 256;
        if (blocks > 2048) blocks = 2048;
        cast_kernel<<<dim3(blocks), dim3(256), 0, stream>>>(in, out, n4);
    };

    cast(hs, hs_b, (size_t)ROWS * HIDDEN);
    cast(Wq, Wq_b, (size_t)HIDDEN * HIDDEN);
    cast(Wk, Wkv_b, (size_t)1024 * HIDDEN);
    cast(Wv, Wkv_b + (size_t)1024 * HIDDEN, (size_t)1024 * HIDDEN);
    cast(Wo, Wo_b, (size_t)HIDDEN * HIDDEN);

    // Q = phi(hs @ Wq^T + bq) -> bf16   [8192 x 4096], 512 wgs
    gemm256<1><<<dim3(512), dim3(512), 0, stream>>>(hs_b, HIDDEN, Wq_b, HIDDEN, bq, nullptr, q_b, ROWS, HIDDEN, HIDDEN);
    // [K|V] fused -> bf16  [8192 x 2048], 256 wgs
    gemm256<2><<<dim3(256), dim3(512), 0, stream>>>(hs_b, HIDDEN, Wkv_b, HIDDEN, bk, bv, kvout, ROWS, 2048, HIDDEN);

    // KV summary + ksum
    kv_partial<<<dim3(32, 16), dim3(256), 0, stream>>>(kvout, kvout + 1024, 2048, kvp, ksp);
    kv_reduce<<<dim3(16, 16), dim3(256), 0, stream>>>(kvp, ksp, kvb, ksum);

    // attn = (q @ kv^T) / (ksum + eps) -> bf16  [8192 x 4096]
    attn_gemm<<<dim3(64, 32), dim3(256), 0, stream>>>(q_b, kvb, ksum, attn_b);

    // out = attn @ Wo^T + bo -> f32
    gemm256<0><<<dim3(512), dim3(512), 0, stream>>>(attn_b, HIDDEN, Wo_b, HIDDEN, bo, nullptr, d_out, ROWS, HIDDEN, HIDDEN);
}

// Round 13
// 843.978 us; speedup vs baseline: 6.3200x; 6.3200x over previous
//
#include <hip/hip_runtime.h>

#define HIDDEN 4096
#define NKV 8
#define NH 32
#define HD 128
#define BATCH 2
#define SEQ 4096
#define ROWS (BATCH*SEQ)   // 8192

typedef short bf16x8 __attribute__((ext_vector_type(8)));
typedef float f32x4 __attribute__((ext_vector_type(4)));

static __device__ __forceinline__ float bf2f(unsigned short u) {
    union { unsigned int i; float f; } c; c.i = ((unsigned int)u) << 16; return c.f;
}
static __device__ __forceinline__ unsigned short f2bf(float x) {
    union { float f; unsigned int i; } c; c.f = x;
    unsigned int r = c.i + 0x7fffu + ((c.i >> 16) & 1u);
    return (unsigned short)(r >> 16);
}

static __device__ __forceinline__ void gl2lds16(const void* g, void* l) {
    __builtin_amdgcn_global_load_lds(
        (const __attribute__((address_space(1))) unsigned int*)g,
        (__attribute__((address_space(3))) unsigned int*)l, 16, 0, 0);
}

#define WGBAR() __builtin_amdgcn_s_barrier()
#define VMW(n) asm volatile("s_waitcnt vmcnt(" #n ")" ::: "memory")
#define LGKM(n) asm volatile("s_waitcnt lgkmcnt(" #n ")" ::: "memory")
#define SCHED_FENCE() __builtin_amdgcn_sched_barrier(0)

// ---------------------------------------------------------------- casts
__global__ __launch_bounds__(256)
void cast_kernel(const float* __restrict__ in, unsigned short* __restrict__ out, int n4) {
    int idx = blockIdx.x * blockDim.x + threadIdx.x;
    int stride = gridDim.x * blockDim.x;
    for (int i = idx; i < n4; i += stride) {
        float4 f = ((const float4*)in)[i];
        ushort4 o;
        o.x = f2bf(f.x); o.y = f2bf(f.y); o.z = f2bf(f.z); o.w = f2bf(f.w);
        ((ushort4*)out)[i] = o;
    }
}

// ---------------------------------------------------------------- 256x256 GEMM, BK=32, 4 bufs x 32KB, dist-2,
// ONE BARRIER PER TWO TILES. Iter k: stage tiles 2k+2,2k+3 (8 loads) at top;
// compute tiles 2k,2k+1 (per-wave counted lgkmcnt pipelines 12 ds_reads under
// 4 MFMA clusters each); VMW(0)+barrier at end (zero vmem in flight across
// barriers; every buffer read only after the barrier following its drain —
// the proven round-9/10 cross-wave invariant). Halving barrier count widens
// the wave-desync window so LDS-read and MFMA pipes overlap across waves
// instead of lockstep-alternating (measured: serialized sum = 2400 cyc/tile).
// LDS panel layout: [r%128][128B], inner = ((r/128)<<6 | k*2) ^ ((r&7)<<4).
// K must be a multiple of 64 (NT even); all launches here have K=4096.
// MODE 0: f32 out, +bias0
// MODE 1: bf16 out, phi(x + bias0)          (Q projection)
// MODE 2: bf16 out, col<1024: phi(x+bias0[col]) else x+bias1[col-1024]  (fused KV)
template<int MODE>
__global__ __launch_bounds__(512, 2)
void gemm256(const unsigned short* __restrict__ A, int lda,
             const unsigned short* __restrict__ B, int ldb,
             const float* __restrict__ bias0, const float* __restrict__ bias1,
             void* __restrict__ Cout, int M, int N, int K)
{
    __shared__ __align__(16) unsigned char sm[131072];   // 4 x (A 16KB + B 16KB)

    const int tid = threadIdx.x;
    const int wid = tid >> 6, lane = tid & 63;
    const int wr = wid >> 2, wc = wid & 3;           // wave grid 2M x 4N
    const int lr = lane & 15, kg = lane >> 4;
    const int swz = (lane & 7) << 4;

    // XCD-aware block swizzle (nwg % 8 == 0 for all launches here)
    int nbx = N >> 8;
    int nwg = nbx * (M >> 8);
    int cpx = nwg >> 3;
    int bid = (int)blockIdx.x;
    int wg = (bid & 7) * cpx + (bid >> 3);
    int bx = wg % nbx, by = wg / nbx;
    int rowBase = by << 8, colBase = bx << 8;

    // staging source offsets: invert layout at linear dest o = i*8192+tid*16
    size_t sA[2], sB[2];
#pragma unroll
    for (int i = 0; i < 2; ++i) {
        int o = i * 8192 + tid * 16;
        int rm = o >> 7;
        int inner = (o & 127) ^ ((rm & 7) << 4);
        int half = inner >> 6;
        int ke = (inner & 63) >> 1;
        sA[i] = (size_t)(rowBase + half * 128 + rm) * lda + ke;
        sB[i] = (size_t)(colBase + half * 128 + rm) * ldb + ke;
    }
    const int ldsW = wid * 1024;

    auto STAGE = [&](int nb, size_t ko) {
        gl2lds16(A + sA[0] + ko, sm + nb + 0 * 8192 + ldsW);
        gl2lds16(A + sA[1] + ko, sm + nb + 1 * 8192 + ldsW);
        gl2lds16(B + sB[0] + ko, sm + nb + 16384 + 0 * 8192 + ldsW);
        gl2lds16(B + sB[1] + ko, sm + nb + 16384 + 1 * 8192 + ldsW);
    };

    const int aRd = (lr << 7) + ((((wr << 6) | (kg << 4))) ^ swz);
    const int bRd = 16384 + ((((wc & 1) * 64 + lr)) << 7)
                  + (((((wc >> 1) << 6) | (kg << 4))) ^ swz);

    auto RA = [&](int cb, int mp) -> bf16x8 {
        return *(const bf16x8*)(sm + cb + aRd + mp * 2048);
    };
    auto RB = [&](int cb, int n) -> bf16x8 {
        return *(const bf16x8*)(sm + cb + bRd + n * 2048);
    };

    f32x4 acc[8][4] = {};
    bf16x8 bfr[4];

    auto MF2 = [&](bf16x8 x0, bf16x8 x1, int m0, int m1) {
        SCHED_FENCE();                     // rule 18: pin MFMAs below the wait
        __builtin_amdgcn_s_setprio(1);
#pragma unroll
        for (int n = 0; n < 4; ++n) {
            acc[m0][n] = __builtin_amdgcn_mfma_f32_16x16x32_bf16(x0, bfr[n], acc[m0][n], 0, 0, 0);
            acc[m1][n] = __builtin_amdgcn_mfma_f32_16x16x32_bf16(x1, bfr[n], acc[m1][n], 0, 0, 0);
        }
        __builtin_amdgcn_s_setprio(0);
        SCHED_FENCE();
    };

    // per-tile compute on buffer cb: 12 ds_reads pipelined under 4 MFMA clusters
    auto TILE = [&](int cb) {
        // G1 (6 reads): all B + A mp0,1
        bfr[0] = RB(cb, 0); bfr[1] = RB(cb, 1); bfr[2] = RB(cb, 2); bfr[3] = RB(cb, 3);
        bf16x8 a0 = RA(cb, 0), a1 = RA(cb, 1);
        SCHED_FENCE();
        // G2 (2): A mp2,3
        bf16x8 a2 = RA(cb, 2), a3 = RA(cb, 3);
        SCHED_FENCE();
        LGKM(2);                // G1 done (G2 in flight)
        MF2(a0, a1, 0, 1);
        // G3 (2): A mp4,5
        a0 = RA(cb, 4); a1 = RA(cb, 5);
        SCHED_FENCE();
        LGKM(2);                // G2 done
        MF2(a2, a3, 2, 3);
        // G4 (2): A mp6,7
        a2 = RA(cb, 6); a3 = RA(cb, 7);
        SCHED_FENCE();
        LGKM(2);                // G3 done
        MF2(a0, a1, 4, 5);
        LGKM(0);                // G4 done (all reads of cb drained -> WAR-safe)
        MF2(a2, a3, 6, 7);
    };

    const int NT = K >> 5;      // K-tiles of 32; NT even
    const int NI = (NT >> 1) - 1;

    // prologue: stage tiles 0,1 into bufs 0,1; publish
    SCHED_FENCE();
    STAGE(0, 0);
    STAGE(32768, 32);
    SCHED_FENCE();
    VMW(0);
    WGBAR();
    SCHED_FENCE();

    int pa = 0;                 // pair base: 0 -> bufs{0,1}, 1 -> bufs{2,3}
    size_t kb = 64;             // element offset of tile 2k+2
    for (int k = 0; k < NI; ++k) {
        const int cb0 = (pa ? 65536 : 0);
        const int cb1 = cb0 + 32768;
        const int nb0 = (pa ? 0 : 65536);
        const int nb1 = nb0 + 32768;
        SCHED_FENCE();
        STAGE(nb0, kb);                 // tile 2k+2
        STAGE(nb1, kb + 32);            // tile 2k+3
        SCHED_FENCE();
        TILE(cb0);                      // tile 2k
        TILE(cb1);                      // tile 2k+1
        VMW(0);                         // drain the 8 stages (cover = 2 tiles)
        WGBAR();                        // publish tiles 2k+2, 2k+3
        SCHED_FENCE();
        pa ^= 1; kb += 64;
    }
    // tail: last two tiles, no staging
    {
        const int cb0 = (pa ? 65536 : 0);
        TILE(cb0);
        TILE(cb0 + 32768);
    }

    // ---- C write
    int r0 = rowBase + wr * 128 + kg * 4;
    int c0 = colBase + wc * 64 + lr;
#pragma unroll
    for (int n = 0; n < 4; ++n) {
        int col = c0 + n * 16;
        float bv;
        if (MODE == 2) bv = (col < 1024) ? bias0[col] : bias1[col - 1024];
        else           bv = bias0[col];
#pragma unroll
        for (int m = 0; m < 8; ++m) {
            int row = r0 + m * 16;
#pragma unroll
            for (int r = 0; r < 4; ++r) {
                float v = acc[m][n][r] + bv;
                if (MODE == 1) v = (v > 0.f) ? v + 1.f : __expf(v);
                if (MODE == 2 && col < 1024) v = (v > 0.f) ? v + 1.f : __expf(v);
                if (MODE == 0) ((float*)Cout)[(size_t)(row + r) * N + col] = v;
                else ((unsigned short*)Cout)[(size_t)(row + r) * N + col] = f2bf(v);
            }
        }
    }
}

// ---------------------------------------------------------------- kv partial: kv[c][d] += v[l,c]*k[l,d] over an L-chunk
__global__ __launch_bounds__(256)
void kv_partial(const unsigned short* __restrict__ Kb, const unsigned short* __restrict__ Vb,
                int ld, float* __restrict__ kvp, float* __restrict__ ksp)
{
    int chunk = blockIdx.x;   // 0..31 (128 rows each)
    int g = blockIdx.y;       // 0..15 = b*8+hkv
    int b = g >> 3, hkv = g & 7;
    __shared__ float kl[32][128];
    __shared__ float vl[32][128];
    int tid = threadIdx.x;
    int c0 = (tid >> 4) * 8, d0 = (tid & 15) * 8;
    float acc[8][8] = {};
    float ksacc = 0.0f;
    size_t rowBase = (size_t)b * SEQ + (size_t)chunk * 128;

    for (int sch = 0; sch < 4; ++sch) {
        __syncthreads();
        for (int t = tid; t < 512; t += 256) {
            int l = t >> 4, col = (t & 15) * 8;
            size_t off = (rowBase + sch * 32 + l) * ld + hkv * HD + col;
            uint4 kr = *(const uint4*)(Kb + off);
            uint4 vr = *(const uint4*)(Vb + off);
            unsigned int ku[4] = {kr.x, kr.y, kr.z, kr.w};
            unsigned int vu[4] = {vr.x, vr.y, vr.z, vr.w};
#pragma unroll
            for (int q = 0; q < 4; ++q) {
                kl[l][col + q * 2]     = bf2f((unsigned short)(ku[q] & 0xffff));
                kl[l][col + q * 2 + 1] = bf2f((unsigned short)(ku[q] >> 16));
                vl[l][col + q * 2]     = bf2f((unsigned short)(vu[q] & 0xffff));
                vl[l][col + q * 2 + 1] = bf2f((unsigned short)(vu[q] >> 16));
            }
        }
        __syncthreads();
        for (int l = 0; l < 32; ++l) {
            float vv[8], kk[8];
#pragma unroll
            for (int x = 0; x < 8; ++x) { vv[x] = vl[l][c0 + x]; kk[x] = kl[l][d0 + x]; }
#pragma unroll
            for (int x = 0; x < 8; ++x)
#pragma unroll
                for (int y = 0; y < 8; ++y)
                    acc[x][y] += vv[x] * kk[y];
        }
        if (tid < 128) {
            for (int l = 0; l < 32; ++l) ksacc += kl[l][tid];
        }
    }
    float* out = kvp + ((size_t)g * 32 + chunk) * (HD * HD);
#pragma unroll
    for (int x = 0; x < 8; ++x)
#pragma unroll
        for (int y = 0; y < 8; ++y)
            out[(c0 + x) * HD + d0 + y] = acc[x][y];
    if (tid < 128) ksp[((size_t)g * 32 + chunk) * HD + tid] = ksacc;
}

// ---------------------------------------------------------------- reduce partials -> kv_bf16, ksum
__global__ __launch_bounds__(256)
void kv_reduce(const float* __restrict__ kvp, const float* __restrict__ ksp,
               unsigned short* __restrict__ kvb, float* __restrict__ ksum)
{
    int slice = blockIdx.x;  // 0..15
    int g = blockIdx.y;      // 0..15
    int tid = threadIdx.x;
    int e = slice * 1024 + tid * 4;
    float4 s = {0.f, 0.f, 0.f, 0.f};
    for (int ch = 0; ch < 32; ++ch) {
        float4 p = *(const float4*)(kvp + ((size_t)g * 32 + ch) * (HD * HD) + e);
        s.x += p.x; s.y += p.y; s.z += p.z; s.w += p.w;
    }
    ushort4 o;
    o.x = f2bf(s.x); o.y = f2bf(s.y); o.z = f2bf(s.z); o.w = f2bf(s.w);
    *(ushort4*)(kvb + (size_t)g * HD * HD + e) = o;
    if (slice == 0 && tid < 128) {
        float ss = 0.f;
        for (int ch = 0; ch < 32; ++ch) ss += ksp[((size_t)g * 32 + ch) * HD + tid];
        ksum[g * HD + tid] = ss;
    }
}

// ---------------------------------------------------------------- attn GEMM: per (row-tile, head): C = q @ kv^T, /(ksum+eps), bf16 out
__global__ __launch_bounds__(256)
void attn_gemm(const unsigned short* __restrict__ Q,
               const unsigned short* __restrict__ KV,
               const float* __restrict__ KS,
               unsigned short* __restrict__ Out)
{
    const int BK = 32;
    __shared__ unsigned short As[128 * BK];
    __shared__ unsigned short Bs[128 * BK];

    int rt = blockIdx.x;   // 0..63
    int h  = blockIdx.y;   // 0..31
    int g = (rt >> 5) * NKV + (h >> 2);
    int rowBase = rt << 7;

    const unsigned short* A = Q + (size_t)h * HD;           // lda = HIDDEN
    const unsigned short* B = KV + (size_t)g * HD * HD;     // ldb = HD
    const float* ks = KS + g * HD;

    int tid = threadIdx.x;
    int wave = tid >> 6, lane = tid & 63;
    int wr = wave >> 1, wc = wave & 1;

    f32x4 acc[4][4] = {};

    int sr = lane >> 2;
    int sc = (lane & 3) * 8;

    const unsigned short* Aw = A + (size_t)(rowBase + wave * 32 + sr) * HIDDEN + sc;
    const unsigned short* Bw = B + (size_t)(wave * 32 + sr) * HD + sc;
    unsigned short* Asw = As + wave * 32 * BK;
    unsigned short* Bsw = Bs + wave * 32 * BK;

    int arow = (wr * 64 + (lane & 15)) * BK + (lane >> 4) * 8;
    int brow = (wc * 64 + (lane & 15)) * BK + (lane >> 4) * 8;

    for (int kt = 0; kt < HD; kt += BK) {
        gl2lds16(Aw + kt, Asw);
        gl2lds16(Aw + kt + (size_t)16 * HIDDEN, Asw + 16 * BK);
        gl2lds16(Bw + kt, Bsw);
        gl2lds16(Bw + kt + (size_t)16 * HD, Bsw + 16 * BK);
        __syncthreads();
        bf16x8 af[4], bfr[4];
#pragma unroll
        for (int i = 0; i < 4; ++i) af[i] = *(const bf16x8*)&As[arow + i * 16 * BK];
#pragma unroll
        for (int j = 0; j < 4; ++j) bfr[j] = *(const bf16x8*)&Bs[brow + j * 16 * BK];
#pragma unroll
        for (int i = 0; i < 4; ++i)
#pragma unroll
            for (int j = 0; j < 4; ++j)
                acc[i][j] = __builtin_amdgcn_mfma_f32_16x16x32_bf16(af[i], bfr[j], acc[i][j], 0, 0, 0);
        __syncthreads();
    }

    int r0 = rowBase + wr * 64 + ((lane >> 4) << 2);
    int c0 = wc * 64 + (lane & 15);
#pragma unroll
    for (int j = 0; j < 4; ++j) {
        int col = c0 + j * 16;
        float inv = 1.0f / (ks[col] + 1e-10f);
#pragma unroll
        for (int i = 0; i < 4; ++i) {
            int row = r0 + i * 16;
#pragma unroll
            for (int r = 0; r < 4; ++r) {
                float v = acc[i][j][r] * inv;
                Out[(size_t)(row + r) * HIDDEN + h * HD + col] = f2bf(v);
            }
        }
    }
}

// ---------------------------------------------------------------- launch
extern "C" void kernel_launch(void* const* d_in, const int* in_sizes, int n_in,
                              void* d_out, int out_size, void* d_ws, size_t ws_size,
                              hipStream_t stream)
{
    const float* hs = (const float*)d_in[0];
    const float* Wq = (const float*)d_in[1];
    const float* bq = (const float*)d_in[2];
    const float* Wk = (const float*)d_in[3];
    const float* bk = (const float*)d_in[4];
    const float* Wv = (const float*)d_in[5];
    const float* bv = (const float*)d_in[6];
    const float* Wo = (const float*)d_in[7];
    const float* bo = (const float*)d_in[8];

    char* ws = (char*)d_ws;
    size_t off = 0;
    auto alloc = [&](size_t bytes) -> char* {
        char* p = ws + off;
        off += (bytes + 255) & ~(size_t)255;
        return p;
    };

    unsigned short* hs_b  = (unsigned short*)alloc((size_t)ROWS * HIDDEN * 2);    // 67 MB (reused by attn out)
    unsigned short* Wq_b  = (unsigned short*)alloc((size_t)HIDDEN * HIDDEN * 2);  // 33.5 MB (reused by kvp)
    unsigned short* Wkv_b = (unsigned short*)alloc((size_t)2048 * HIDDEN * 2);    // 16.8 MB (Wk rows 0..1023, Wv rows 1024..2047)
    unsigned short* Wo_b  = (unsigned short*)alloc((size_t)HIDDEN * HIDDEN * 2);  // 33.5 MB
    unsigned short* kvout = (unsigned short*)alloc((size_t)ROWS * 2048 * 2);      // 33.5 MB [row][K(1024)|V(1024)]
    float* ksp   = (float*)alloc((size_t)16 * 32 * HD * 4);
    unsigned short* kvb = (unsigned short*)alloc((size_t)16 * HD * HD * 2);
    float* ksum  = (float*)alloc((size_t)16 * HD * 4);

    // aliases (lifetime-disjoint):
    float* kvp = (float*)Wq_b;                    // Wq dead after Q GEMM
    unsigned short* attn_b = hs_b;                // hs dead after KV GEMM
    unsigned short* q_b = (unsigned short*)d_out; // front 67 MB of d_out, dead before final GEMM writes

    (void)in_sizes; (void)n_in; (void)out_size; (void)ws_size;

    auto cast = [&](const float* in, unsigned short* out, size_t n) {
        int n4 = (int)(n / 4);
        int blocks = (n4 + 255) / 256;
        if (blocks > 2048) blocks = 2048;
        cast_kernel<<<dim3(blocks), dim3(256), 0, stream>>>(in, out, n4);
    };

    cast(hs, hs_b, (size_t)ROWS * HIDDEN);
    cast(Wq, Wq_b, (size_t)HIDDEN * HIDDEN);
    cast(Wk, Wkv_b, (size_t)1024 * HIDDEN);
    cast(Wv, Wkv_b + (size_t)1024 * HIDDEN, (size_t)1024 * HIDDEN);
    cast(Wo, Wo_b, (size_t)HIDDEN * HIDDEN);

    // Q = phi(hs @ Wq^T + bq) -> bf16   [8192 x 4096], 512 wgs
    gemm256<1><<<dim3(512), dim3(512), 0, stream>>>(hs_b, HIDDEN, Wq_b, HIDDEN, bq, nullptr, q_b, ROWS, HIDDEN, HIDDEN);
    // [K|V] fused -> bf16  [8192 x 2048], 256 wgs
    gemm256<2><<<dim3(256), dim3(512), 0, stream>>>(hs_b, HIDDEN, Wkv_b, HIDDEN, bk, bv, kvout, ROWS, 2048, HIDDEN);

    // KV summary + ksum
    kv_partial<<<dim3(32, 16), dim3(256), 0, stream>>>(kvout, kvout + 1024, 2048, kvp, ksp);
    kv_reduce<<<dim3(16, 16), dim3(256), 0, stream>>>(kvp, ksp, kvb, ksum);

    // attn = (q @ kv^T) / (ksum + eps) -> bf16  [8192 x 4096]
    attn_gemm<<<dim3(64, 32), dim3(256), 0, stream>>>(q_b, kvb, ksum, attn_b);

    // out = attn @ Wo^T + bo -> f32
    gemm256<0><<<dim3(512), dim3(512), 0, stream>>>(attn_b, HIDDEN, Wo_b, HIDDEN, bo, nullptr, d_out, ROWS, HIDDEN, HIDDEN);
}

// Round 14
// 772.735 us; speedup vs baseline: 6.9026x; 1.0922x over previous
//
#include <hip/hip_runtime.h>

#define HIDDEN 4096
#define NKV 8
#define NH 32
#define HD 128
#define BATCH 2
#define SEQ 4096
#define ROWS (BATCH*SEQ)   // 8192

typedef short bf16x8 __attribute__((ext_vector_type(8)));
typedef float f32x4 __attribute__((ext_vector_type(4)));

static __device__ __forceinline__ float bf2f(unsigned short u) {
    union { unsigned int i; float f; } c; c.i = ((unsigned int)u) << 16; return c.f;
}
static __device__ __forceinline__ unsigned short f2bf(float x) {
    union { float f; unsigned int i; } c; c.f = x;
    unsigned int r = c.i + 0x7fffu + ((c.i >> 16) & 1u);
    return (unsigned short)(r >> 16);
}

static __device__ __forceinline__ void gl2lds16(const void* g, void* l) {
    __builtin_amdgcn_global_load_lds(
        (const __attribute__((address_space(1))) unsigned int*)g,
        (__attribute__((address_space(3))) unsigned int*)l, 16, 0, 0);
}

#define WGBAR() __builtin_amdgcn_s_barrier()
#define VMW(n) asm volatile("s_waitcnt vmcnt(" #n ")" ::: "memory")
#define LGKM(n) asm volatile("s_waitcnt lgkmcnt(" #n ")" ::: "memory")
#define SCHED_FENCE() __builtin_amdgcn_sched_barrier(0)

// ---------------------------------------------------------------- casts
__global__ __launch_bounds__(256)
void cast_kernel(const float* __restrict__ in, unsigned short* __restrict__ out, int n4) {
    int idx = blockIdx.x * blockDim.x + threadIdx.x;
    int stride = gridDim.x * blockDim.x;
    for (int i = idx; i < n4; i += stride) {
        float4 f = ((const float4*)in)[i];
        ushort4 o;
        o.x = f2bf(f.x); o.y = f2bf(f.y); o.z = f2bf(f.z); o.w = f2bf(f.w);
        ((ushort4*)out)[i] = o;
    }
}

// ---------------------------------------------------------------- 256x256 GEMM, BK=64, 2 bufs x 64KB, dist-1 (round-9
// schedule, de-pinned). All 8 staging loads issued at TOP of the K-tile;
// per-wave counted lgkmcnt pipelines the 16 ds_reads under 4 MFMA clusters;
// VMW(0)+barrier at end publishes staged data workgroup-wide (zero vmem in
// flight across barriers — the proven cross-wave invariant). Fences trimmed
// to the rule-18 minimum (m141: over-pinning defeats the compiler scheduler):
// one after each counted LGKM (MFMA hoist guard), one after each barrier
// (next-tile ds_read hoist guard). Memory-op ordering across the waitcnt asms
// is pinned by their "memory" clobbers; register deps are compiler-tracked.
// LDS: per dbuf, A half0/half1 + B half0/half1, each 128 rows x 64 cols bf16,
// colb ^= ((row&7)<<4) swizzle (applied on global src; LDS dest linear).
// MODE 0: f32 out, +bias0
// MODE 1: bf16 out, phi(x + bias0)          (Q projection)
// MODE 2: bf16 out, col<1024: phi(x+bias0[col]) else x+bias1[col-1024]  (fused KV)
template<int MODE>
__global__ __launch_bounds__(512, 2)
void gemm256(const unsigned short* __restrict__ A, int lda,
             const unsigned short* __restrict__ B, int ldb,
             const float* __restrict__ bias0, const float* __restrict__ bias1,
             void* __restrict__ Cout, int M, int N, int K)
{
    __shared__ __align__(16) unsigned char sm[131072];

    const int tid = threadIdx.x;
    const int wid = tid >> 6, lane = tid & 63;
    const int wr = wid >> 2, wc = wid & 3;           // wave grid 2M x 4N
    const int lr = lane & 15, kg = lane >> 4;
    const int lswz = (lane & 7) << 4;

    // XCD-aware block swizzle (nwg % 8 == 0 for all launches here)
    int nbx = N >> 8;
    int nwg = nbx * (M >> 8);
    int cpx = nwg >> 3;
    int bid = (int)blockIdx.x;
    int wg = (bid & 7) * cpx + (bid >> 3);
    int bx = wg % nbx, by = wg / nbx;
    int rowBase = by << 8, colBase = bx << 8;

    // per-thread staging source offsets (global addr pre-swizzled; LDS dest linear)
    size_t sA[2][2], sB[2][2];   // [half][insn]
#pragma unroll
    for (int h = 0; h < 2; ++h)
#pragma unroll
        for (int i = 0; i < 2; ++i) {
            int o = i * 8192 + wid * 1024 + lane * 16;    // byte offset in 16KB half
            int row = o >> 7;                              // 0..127
            int ce = ((o & 127) ^ ((row & 7) << 4)) >> 1;  // source col element 0..63
            sA[h][i] = (size_t)(rowBase + h * 128 + row) * lda + ce;
            sB[h][i] = (size_t)(colBase + h * 128 + row) * ldb + ce;
        }
    const int ldsW = wid * 1024;

    auto SA = [&](int nb, int h, int i, size_t ko) {
        gl2lds16(A + sA[h][i] + ko, sm + nb + h * 16384 + i * 8192 + ldsW);
    };
    auto SB = [&](int nb, int h, int i, size_t ko) {
        gl2lds16(B + sB[h][i] + ko, sm + nb + 32768 + h * 16384 + i * 8192 + ldsW);
    };
    auto STAGE = [&](int buf, size_t ko) {
        int nb = buf << 16;
        SB(nb, 0, 0, ko); SB(nb, 0, 1, ko); SB(nb, 1, 0, ko); SB(nb, 1, 1, ko);
        SA(nb, 0, 0, ko); SA(nb, 1, 0, ko); SA(nb, 0, 1, ko); SA(nb, 1, 1, ko);
    };

    // LDS read addressing (swizzled)
    const int aRd = wr * 16384 + (lr << 7);
    const int bRd = 32768 + (wc >> 1) * 16384 + (((wc & 1) * 64 + lr) << 7);
    const int kcol0 = (kg * 16) ^ lswz;
    const int kcol1 = (64 + kg * 16) ^ lswz;

    auto RA = [&](int cb, int mp, int ks) -> bf16x8 {
        return *(const bf16x8*)(sm + cb + aRd + mp * 2048 + (ks ? kcol1 : kcol0));
    };
    auto RB = [&](int cb, int n, int ks) -> bf16x8 {
        return *(const bf16x8*)(sm + cb + bRd + n * 2048 + (ks ? kcol1 : kcol0));
    };

    f32x4 acc[8][4] = {};
    bf16x8 bfr[4][2];

    // MFMA cluster: caller has already placed the counted lgkm wait.
    // Leading fence = rule-18 guard (MFMA can't hoist above the wait).
    // No trailing fence: MFMAs may sink into the following read region.
    auto MF = [&](bf16x8 a0, bf16x8 a1, bf16x8 a2, bf16x8 a3, int m0, int m1) {
        SCHED_FENCE();
        __builtin_amdgcn_s_setprio(1);
#pragma unroll
        for (int n = 0; n < 4; ++n) {
            acc[m0][n] = __builtin_amdgcn_mfma_f32_16x16x32_bf16(a0, bfr[n][0], acc[m0][n], 0, 0, 0);
            acc[m0][n] = __builtin_amdgcn_mfma_f32_16x16x32_bf16(a1, bfr[n][1], acc[m0][n], 0, 0, 0);
            acc[m1][n] = __builtin_amdgcn_mfma_f32_16x16x32_bf16(a2, bfr[n][0], acc[m1][n], 0, 0, 0);
            acc[m1][n] = __builtin_amdgcn_mfma_f32_16x16x32_bf16(a3, bfr[n][1], acc[m1][n], 0, 0, 0);
        }
        __builtin_amdgcn_s_setprio(0);
    };

    const int NT = K >> 6;

    // prologue: stage tile 0, publish
    STAGE(0, 0);
    VMW(0);
    WGBAR();
    SCHED_FENCE();

    int cur = 0;
    for (int t = 0; t < NT; ++t) {
        const int cb = cur << 16;
        if (t + 1 < NT) {
            STAGE(cur ^ 1, (size_t)(t + 1) * 64);   // 8 vmem; drained at tile end
        }
        // ---- G1: 12 ds: all B + A mp0,1
        bf16x8 a0 = RA(cb, 0, 0), a1 = RA(cb, 0, 1), a2 = RA(cb, 1, 0), a3 = RA(cb, 1, 1);
#pragma unroll
        for (int n = 0; n < 4; ++n) { bfr[n][0] = RB(cb, n, 0); bfr[n][1] = RB(cb, n, 1); }
        // ---- G2: 4 ds: A mp2,3
        bf16x8 b0 = RA(cb, 2, 0), b1 = RA(cb, 2, 1), b2 = RA(cb, 3, 0), b3 = RA(cb, 3, 1);
        LGKM(4);            // G1 done (G2 in flight)
        MF(a0, a1, a2, a3, 0, 1);
        // ---- G3: 4 ds: A mp4,5
        a0 = RA(cb, 4, 0); a1 = RA(cb, 4, 1); a2 = RA(cb, 5, 0); a3 = RA(cb, 5, 1);
        LGKM(4);            // G2 done
        MF(b0, b1, b2, b3, 2, 3);
        // ---- G4: 4 ds: A mp6,7
        b0 = RA(cb, 6, 0); b1 = RA(cb, 6, 1); b2 = RA(cb, 7, 0); b3 = RA(cb, 7, 1);
        LGKM(4);            // G3 done
        MF(a0, a1, a2, a3, 4, 5);
        LGKM(0);            // all cb reads drained
        MF(b0, b1, b2, b3, 6, 7);
        if (t + 1 < NT) {
            VMW(0);         // all stages landed -> barrier publishes workgroup-wide
            WGBAR();
            SCHED_FENCE();
        }
        cur ^= 1;
    }

    // ---- C write
    int r0 = rowBase + wr * 128 + kg * 4;
    int c0 = colBase + wc * 64 + lr;
#pragma unroll
    for (int n = 0; n < 4; ++n) {
        int col = c0 + n * 16;
        float bv;
        if (MODE == 2) bv = (col < 1024) ? bias0[col] : bias1[col - 1024];
        else           bv = bias0[col];
#pragma unroll
        for (int m = 0; m < 8; ++m) {
            int row = r0 + m * 16;
#pragma unroll
            for (int r = 0; r < 4; ++r) {
                float v = acc[m][n][r] + bv;
                if (MODE == 1) v = (v > 0.f) ? v + 1.f : __expf(v);
                if (MODE == 2 && col < 1024) v = (v > 0.f) ? v + 1.f : __expf(v);
                if (MODE == 0) ((float*)Cout)[(size_t)(row + r) * N + col] = v;
                else ((unsigned short*)Cout)[(size_t)(row + r) * N + col] = f2bf(v);
            }
        }
    }
}

// ---------------------------------------------------------------- kv partial: kv[c][d] += v[l,c]*k[l,d] over an L-chunk
__global__ __launch_bounds__(256)
void kv_partial(const unsigned short* __restrict__ Kb, const unsigned short* __restrict__ Vb,
                int ld, float* __restrict__ kvp, float* __restrict__ ksp)
{
    int chunk = blockIdx.x;   // 0..31 (128 rows each)
    int g = blockIdx.y;       // 0..15 = b*8+hkv
    int b = g >> 3, hkv = g & 7;
    __shared__ float kl[32][128];
    __shared__ float vl[32][128];
    int tid = threadIdx.x;
    int c0 = (tid >> 4) * 8, d0 = (tid & 15) * 8;
    float acc[8][8] = {};
    float ksacc = 0.0f;
    size_t rowBase = (size_t)b * SEQ + (size_t)chunk * 128;

    for (int sch = 0; sch < 4; ++sch) {
        __syncthreads();
        for (int t = tid; t < 512; t += 256) {
            int l = t >> 4, col = (t & 15) * 8;
            size_t off = (rowBase + sch * 32 + l) * ld + hkv * HD + col;
            uint4 kr = *(const uint4*)(Kb + off);
            uint4 vr = *(const uint4*)(Vb + off);
            unsigned int ku[4] = {kr.x, kr.y, kr.z, kr.w};
            unsigned int vu[4] = {vr.x, vr.y, vr.z, vr.w};
#pragma unroll
            for (int q = 0; q < 4; ++q) {
                kl[l][col + q * 2]     = bf2f((unsigned short)(ku[q] & 0xffff));
                kl[l][col + q * 2 + 1] = bf2f((unsigned short)(ku[q] >> 16));
                vl[l][col + q * 2]     = bf2f((unsigned short)(vu[q] & 0xffff));
                vl[l][col + q * 2 + 1] = bf2f((unsigned short)(vu[q] >> 16));
            }
        }
        __syncthreads();
        for (int l = 0; l < 32; ++l) {
            float vv[8], kk[8];
#pragma unroll
            for (int x = 0; x < 8; ++x) { vv[x] = vl[l][c0 + x]; kk[x] = kl[l][d0 + x]; }
#pragma unroll
            for (int x = 0; x < 8; ++x)
#pragma unroll
                for (int y = 0; y < 8; ++y)
                    acc[x][y] += vv[x] * kk[y];
        }
        if (tid < 128) {
            for (int l = 0; l < 32; ++l) ksacc += kl[l][tid];
        }
    }
    float* out = kvp + ((size_t)g * 32 + chunk) * (HD * HD);
#pragma unroll
    for (int x = 0; x < 8; ++x)
#pragma unroll
        for (int y = 0; y < 8; ++y)
            out[(c0 + x) * HD + d0 + y] = acc[x][y];
    if (tid < 128) ksp[((size_t)g * 32 + chunk) * HD + tid] = ksacc;
}

// ---------------------------------------------------------------- reduce partials -> kv_bf16, ksum
__global__ __launch_bounds__(256)
void kv_reduce(const float* __restrict__ kvp, const float* __restrict__ ksp,
               unsigned short* __restrict__ kvb, float* __restrict__ ksum)
{
    int slice = blockIdx.x;  // 0..15
    int g = blockIdx.y;      // 0..15
    int tid = threadIdx.x;
    int e = slice * 1024 + tid * 4;
    float4 s = {0.f, 0.f, 0.f, 0.f};
    for (int ch = 0; ch < 32; ++ch) {
        float4 p = *(const float4*)(kvp + ((size_t)g * 32 + ch) * (HD * HD) + e);
        s.x += p.x; s.y += p.y; s.z += p.z; s.w += p.w;
    }
    ushort4 o;
    o.x = f2bf(s.x); o.y = f2bf(s.y); o.z = f2bf(s.z); o.w = f2bf(s.w);
    *(ushort4*)(kvb + (size_t)g * HD * HD + e) = o;
    if (slice == 0 && tid < 128) {
        float ss = 0.f;
        for (int ch = 0; ch < 32; ++ch) ss += ksp[((size_t)g * 32 + ch) * HD + tid];
        ksum[g * HD + tid] = ss;
    }
}

// ---------------------------------------------------------------- attn GEMM: per (row-tile, head): C = q @ kv^T, /(ksum+eps), bf16 out
__global__ __launch_bounds__(256)
void attn_gemm(const unsigned short* __restrict__ Q,
               const unsigned short* __restrict__ KV,
               const float* __restrict__ KS,
               unsigned short* __restrict__ Out)
{
    const int BK = 32;
    __shared__ unsigned short As[128 * BK];
    __shared__ unsigned short Bs[128 * BK];

    int rt = blockIdx.x;   // 0..63
    int h  = blockIdx.y;   // 0..31
    int g = (rt >> 5) * NKV + (h >> 2);
    int rowBase = rt << 7;

    const unsigned short* A = Q + (size_t)h * HD;           // lda = HIDDEN
    const unsigned short* B = KV + (size_t)g * HD * HD;     // ldb = HD
    const float* ks = KS + g * HD;

    int tid = threadIdx.x;
    int wave = tid >> 6, lane = tid & 63;
    int wr = wave >> 1, wc = wave & 1;

    f32x4 acc[4][4] = {};

    int sr = lane >> 2;
    int sc = (lane & 3) * 8;

    const unsigned short* Aw = A + (size_t)(rowBase + wave * 32 + sr) * HIDDEN + sc;
    const unsigned short* Bw = B + (size_t)(wave * 32 + sr) * HD + sc;
    unsigned short* Asw = As + wave * 32 * BK;
    unsigned short* Bsw = Bs + wave * 32 * BK;

    int arow = (wr * 64 + (lane & 15)) * BK + (lane >> 4) * 8;
    int brow = (wc * 64 + (lane & 15)) * BK + (lane >> 4) * 8;

    for (int kt = 0; kt < HD; kt += BK) {
        gl2lds16(Aw + kt, Asw);
        gl2lds16(Aw + kt + (size_t)16 * HIDDEN, Asw + 16 * BK);
        gl2lds16(Bw + kt, Bsw);
        gl2lds16(Bw + kt + (size_t)16 * HD, Bsw + 16 * BK);
        __syncthreads();
        bf16x8 af[4], bfr[4];
#pragma unroll
        for (int i = 0; i < 4; ++i) af[i] = *(const bf16x8*)&As[arow + i * 16 * BK];
#pragma unroll
        for (int j = 0; j < 4; ++j) bfr[j] = *(const bf16x8*)&Bs[brow + j * 16 * BK];
#pragma unroll
        for (int i = 0; i < 4; ++i)
#pragma unroll
            for (int j = 0; j < 4; ++j)
                acc[i][j] = __builtin_amdgcn_mfma_f32_16x16x32_bf16(af[i], bfr[j], acc[i][j], 0, 0, 0);
        __syncthreads();
    }

    int r0 = rowBase + wr * 64 + ((lane >> 4) << 2);
    int c0 = wc * 64 + (lane & 15);
#pragma unroll
    for (int j = 0; j < 4; ++j) {
        int col = c0 + j * 16;
        float inv = 1.0f / (ks[col] + 1e-10f);
#pragma unroll
        for (int i = 0; i < 4; ++i) {
            int row = r0 + i * 16;
#pragma unroll
            for (int r = 0; r < 4; ++r) {
                float v = acc[i][j][r] * inv;
                Out[(size_t)(row + r) * HIDDEN + h * HD + col] = f2bf(v);
            }
        }
    }
}

// ---------------------------------------------------------------- launch
extern "C" void kernel_launch(void* const* d_in, const int* in_sizes, int n_in,
                              void* d_out, int out_size, void* d_ws, size_t ws_size,
                              hipStream_t stream)
{
    const float* hs = (const float*)d_in[0];
    const float* Wq = (const float*)d_in[1];
    const float* bq = (const float*)d_in[2];
    const float* Wk = (const float*)d_in[3];
    const float* bk = (const float*)d_in[4];
    const float* Wv = (const float*)d_in[5];
    const float* bv = (const float*)d_in[6];
    const float* Wo = (const float*)d_in[7];
    const float* bo = (const float*)d_in[8];

    char* ws = (char*)d_ws;
    size_t off = 0;
    auto alloc = [&](size_t bytes) -> char* {
        char* p = ws + off;
        off += (bytes + 255) & ~(size_t)255;
        return p;
    };

    unsigned short* hs_b  = (unsigned short*)alloc((size_t)ROWS * HIDDEN * 2);    // 67 MB (reused by attn out)
    unsigned short* Wq_b  = (unsigned short*)alloc((size_t)HIDDEN * HIDDEN * 2);  // 33.5 MB (reused by kvp)
    unsigned short* Wkv_b = (unsigned short*)alloc((size_t)2048 * HIDDEN * 2);    // 16.8 MB (Wk rows 0..1023, Wv rows 1024..2047)
    unsigned short* Wo_b  = (unsigned short*)alloc((size_t)HIDDEN * HIDDEN * 2);  // 33.5 MB
    unsigned short* kvout = (unsigned short*)alloc((size_t)ROWS * 2048 * 2);      // 33.5 MB [row][K(1024)|V(1024)]
    float* ksp   = (float*)alloc((size_t)16 * 32 * HD * 4);
    unsigned short* kvb = (unsigned short*)alloc((size_t)16 * HD * HD * 2);
    float* ksum  = (float*)alloc((size_t)16 * HD * 4);

    // aliases (lifetime-disjoint):
    float* kvp = (float*)Wq_b;                    // Wq dead after Q GEMM
    unsigned short* attn_b = hs_b;                // hs dead after KV GEMM
    unsigned short* q_b = (unsigned short*)d_out; // front 67 MB of d_out, dead before final GEMM writes

    (void)in_sizes; (void)n_in; (void)out_size; (void)ws_size;

    auto cast = [&](const float* in, unsigned short* out, size_t n) {
        int n4 = (int)(n / 4);
        int blocks = (n4 + 255) / 256;
        if (blocks > 2048) blocks = 2048;
        cast_kernel<<<dim3(blocks), dim3(256), 0, stream>>>(in, out, n4);
    };

    cast(hs, hs_b, (size_t)ROWS * HIDDEN);
    cast(Wq, Wq_b, (size_t)HIDDEN * HIDDEN);
    cast(Wk, Wkv_b, (size_t)1024 * HIDDEN);
    cast(Wv, Wkv_b + (size_t)1024 * HIDDEN, (size_t)1024 * HIDDEN);
    cast(Wo, Wo_b, (size_t)HIDDEN * HIDDEN);

    // Q = phi(hs @ Wq^T + bq) -> bf16   [8192 x 4096], 512 wgs
    gemm256<1><<<dim3(512), dim3(512), 0, stream>>>(hs_b, HIDDEN, Wq_b, HIDDEN, bq, nullptr, q_b, ROWS, HIDDEN, HIDDEN);
    // [K|V] fused -> bf16  [8192 x 2048], 256 wgs
    gemm256<2><<<dim3(256), dim3(512), 0, stream>>>(hs_b, HIDDEN, Wkv_b, HIDDEN, bk, bv, kvout, ROWS, 2048, HIDDEN);

    // KV summary + ksum
    kv_partial<<<dim3(32, 16), dim3(256), 0, stream>>>(kvout, kvout + 1024, 2048, kvp, ksp);
    kv_reduce<<<dim3(16, 16), dim3(256), 0, stream>>>(kvp, ksp, kvb, ksum);

    // attn = (q @ kv^T) / (ksum + eps) -> bf16  [8192 x 4096]
    attn_gemm<<<dim3(64, 32), dim3(256), 0, stream>>>(q_b, kvb, ksum, attn_b);

    // out = attn @ Wo^T + bo -> f32
    gemm256<0><<<dim3(512), dim3(512), 0, stream>>>(attn_b, HIDDEN, Wo_b, HIDDEN, bo, nullptr, d_out, ROWS, HIDDEN, HIDDEN);
}

// Round 15
// 760.098 us; speedup vs baseline: 7.0174x; 1.0166x over previous
//
#include <hip/hip_runtime.h>

#define HIDDEN 4096
#define NKV 8
#define NH 32
#define HD 128
#define BATCH 2
#define SEQ 4096
#define ROWS (BATCH*SEQ)   // 8192

typedef short bf16x8 __attribute__((ext_vector_type(8)));
typedef float f32x4 __attribute__((ext_vector_type(4)));

static __device__ __forceinline__ float bf2f(unsigned short u) {
    union { unsigned int i; float f; } c; c.i = ((unsigned int)u) << 16; return c.f;
}
static __device__ __forceinline__ unsigned short f2bf(float x) {
    union { float f; unsigned int i; } c; c.f = x;
    unsigned int r = c.i + 0x7fffu + ((c.i >> 16) & 1u);
    return (unsigned short)(r >> 16);
}

static __device__ __forceinline__ void gl2lds16(const void* g, void* l) {
    __builtin_amdgcn_global_load_lds(
        (const __attribute__((address_space(1))) unsigned int*)g,
        (__attribute__((address_space(3))) unsigned int*)l, 16, 0, 0);
}

#define WGBAR() __builtin_amdgcn_s_barrier()
#define VMW(n) asm volatile("s_waitcnt vmcnt(" #n ")" ::: "memory")
#define SCHED_FENCE() __builtin_amdgcn_sched_barrier(0)

// ---------------------------------------------------------------- fused segmented cast (5 segments, 1 launch)
struct CastSegs {
    const float* in[5];
    unsigned short* out[5];
    int n4[5];      // float4 counts
    int cum[5];     // exclusive prefix
    int total;
};

__global__ __launch_bounds__(256)
void cast5_kernel(CastSegs s) {
    int idx = blockIdx.x * blockDim.x + threadIdx.x;
    int stride = gridDim.x * blockDim.x;
    for (int i = idx; i < s.total; i += stride) {
        int seg = 0;
        if (i >= s.cum[1]) seg = 1;
        if (i >= s.cum[2]) seg = 2;
        if (i >= s.cum[3]) seg = 3;
        if (i >= s.cum[4]) seg = 4;
        int j = i - s.cum[seg];
        float4 f = ((const float4*)s.in[seg])[j];
        ushort4 o;
        o.x = f2bf(f.x); o.y = f2bf(f.y); o.z = f2bf(f.z); o.w = f2bf(f.w);
        ((ushort4*)s.out[seg])[j] = o;
    }
}

// ---------------------------------------------------------------- 256x256 GEMM, BK=64, 2 bufs x 64KB, dist-1.
// COMPILER-SCHEDULED tile body: no asm waits/fences inside the tile — the
// ds_read->MFMA register deps are compiler-tracked (it emits fine-grained
// lgkmcnt itself, finer than source-level counted waits). Only hazard the
// compiler can't see is global_load_lds (no dest reg): covered by the
// skeleton VMW(0) -> s_barrier -> sched_fence at tile end (zero vmem in
// flight across barriers; buffer read only after the barrier following its
// drain — the proven cross-wave invariant). MFMAs may sink below the
// barrier freely (register-only) giving natural cross-tile overlap.
// LDS: per dbuf, A half0/half1 + B half0/half1, each 128 rows x 64 cols bf16,
// colb ^= ((row&7)<<4) swizzle (applied on global src; LDS dest linear).
// MODE 0: f32 out, +bias0
// MODE 1: bf16 out, phi(x + bias0)          (Q projection)
// MODE 2: bf16 out, col<1024: phi(x+bias0[col]) else x+bias1[col-1024]  (fused KV)
template<int MODE>
__global__ __launch_bounds__(512, 2)
void gemm256(const unsigned short* __restrict__ A, int lda,
             const unsigned short* __restrict__ B, int ldb,
             const float* __restrict__ bias0, const float* __restrict__ bias1,
             void* __restrict__ Cout, int M, int N, int K)
{
    __shared__ __align__(16) unsigned char sm[131072];

    const int tid = threadIdx.x;
    const int wid = tid >> 6, lane = tid & 63;
    const int wr = wid >> 2, wc = wid & 3;           // wave grid 2M x 4N
    const int lr = lane & 15, kg = lane >> 4;
    const int lswz = (lane & 7) << 4;

    // XCD-aware block swizzle (nwg % 8 == 0 for all launches here)
    int nbx = N >> 8;
    int nwg = nbx * (M >> 8);
    int cpx = nwg >> 3;
    int bid = (int)blockIdx.x;
    int wg = (bid & 7) * cpx + (bid >> 3);
    int bx = wg % nbx, by = wg / nbx;
    int rowBase = by << 8, colBase = bx << 8;

    // per-thread staging source offsets (global addr pre-swizzled; LDS dest linear)
    size_t sA[2][2], sB[2][2];   // [half][insn]
#pragma unroll
    for (int h = 0; h < 2; ++h)
#pragma unroll
        for (int i = 0; i < 2; ++i) {
            int o = i * 8192 + wid * 1024 + lane * 16;    // byte offset in 16KB half
            int row = o >> 7;                              // 0..127
            int ce = ((o & 127) ^ ((row & 7) << 4)) >> 1;  // source col element 0..63
            sA[h][i] = (size_t)(rowBase + h * 128 + row) * lda + ce;
            sB[h][i] = (size_t)(colBase + h * 128 + row) * ldb + ce;
        }
    const int ldsW = wid * 1024;

    auto SA = [&](int nb, int h, int i, size_t ko) {
        gl2lds16(A + sA[h][i] + ko, sm + nb + h * 16384 + i * 8192 + ldsW);
    };
    auto SB = [&](int nb, int h, int i, size_t ko) {
        gl2lds16(B + sB[h][i] + ko, sm + nb + 32768 + h * 16384 + i * 8192 + ldsW);
    };
    auto STAGE = [&](int buf, size_t ko) {
        int nb = buf << 16;
        SB(nb, 0, 0, ko); SB(nb, 0, 1, ko); SB(nb, 1, 0, ko); SB(nb, 1, 1, ko);
        SA(nb, 0, 0, ko); SA(nb, 1, 0, ko); SA(nb, 0, 1, ko); SA(nb, 1, 1, ko);
    };

    // LDS read addressing (swizzled)
    const int aRd = wr * 16384 + (lr << 7);
    const int bRd = 32768 + (wc >> 1) * 16384 + (((wc & 1) * 64 + lr) << 7);
    const int kcol0 = (kg * 16) ^ lswz;
    const int kcol1 = (64 + kg * 16) ^ lswz;

    auto RA = [&](int cb, int mp, int ks) -> bf16x8 {
        return *(const bf16x8*)(sm + cb + aRd + mp * 2048 + (ks ? kcol1 : kcol0));
    };
    auto RB = [&](int cb, int n, int ks) -> bf16x8 {
        return *(const bf16x8*)(sm + cb + bRd + n * 2048 + (ks ? kcol1 : kcol0));
    };

    f32x4 acc[8][4] = {};
    bf16x8 bfr[4][2];

    // MFMA cluster: plain C++, compiler-scheduled (reg deps auto-waited).
    auto MF = [&](bf16x8 a0, bf16x8 a1, bf16x8 a2, bf16x8 a3, int m0, int m1) {
#pragma unroll
        for (int n = 0; n < 4; ++n) {
            acc[m0][n] = __builtin_amdgcn_mfma_f32_16x16x32_bf16(a0, bfr[n][0], acc[m0][n], 0, 0, 0);
            acc[m0][n] = __builtin_amdgcn_mfma_f32_16x16x32_bf16(a1, bfr[n][1], acc[m0][n], 0, 0, 0);
            acc[m1][n] = __builtin_amdgcn_mfma_f32_16x16x32_bf16(a2, bfr[n][0], acc[m1][n], 0, 0, 0);
            acc[m1][n] = __builtin_amdgcn_mfma_f32_16x16x32_bf16(a3, bfr[n][1], acc[m1][n], 0, 0, 0);
        }
    };

    const int NT = K >> 6;

    // prologue: stage tile 0, publish
    STAGE(0, 0);
    VMW(0);
    WGBAR();
    SCHED_FENCE();

    int cur = 0;
    for (int t = 0; t < NT; ++t) {
        const int cb = cur << 16;
        if (t + 1 < NT) {
            STAGE(cur ^ 1, (size_t)(t + 1) * 64);   // 8 vmem; drained at tile end
        }
        // reads + MFMA clusters, grouped as hints; compiler interleaves freely
        bf16x8 a0 = RA(cb, 0, 0), a1 = RA(cb, 0, 1), a2 = RA(cb, 1, 0), a3 = RA(cb, 1, 1);
#pragma unroll
        for (int n = 0; n < 4; ++n) { bfr[n][0] = RB(cb, n, 0); bfr[n][1] = RB(cb, n, 1); }
        bf16x8 b0 = RA(cb, 2, 0), b1 = RA(cb, 2, 1), b2 = RA(cb, 3, 0), b3 = RA(cb, 3, 1);
        MF(a0, a1, a2, a3, 0, 1);
        a0 = RA(cb, 4, 0); a1 = RA(cb, 4, 1); a2 = RA(cb, 5, 0); a3 = RA(cb, 5, 1);
        MF(b0, b1, b2, b3, 2, 3);
        b0 = RA(cb, 6, 0); b1 = RA(cb, 6, 1); b2 = RA(cb, 7, 0); b3 = RA(cb, 7, 1);
        MF(a0, a1, a2, a3, 4, 5);
        MF(b0, b1, b2, b3, 6, 7);
        if (t + 1 < NT) {
            VMW(0);         // all stages landed (compiler can't track gl2lds)
            WGBAR();        // publish workgroup-wide
            SCHED_FENCE();  // keep next-tile ds_reads below the barrier
        }
        cur ^= 1;
    }

    // ---- C write
    int r0 = rowBase + wr * 128 + kg * 4;
    int c0 = colBase + wc * 64 + lr;
#pragma unroll
    for (int n = 0; n < 4; ++n) {
        int col = c0 + n * 16;
        float bv;
        if (MODE == 2) bv = (col < 1024) ? bias0[col] : bias1[col - 1024];
        else           bv = bias0[col];
#pragma unroll
        for (int m = 0; m < 8; ++m) {
            int row = r0 + m * 16;
#pragma unroll
            for (int r = 0; r < 4; ++r) {
                float v = acc[m][n][r] + bv;
                if (MODE == 1) v = (v > 0.f) ? v + 1.f : __expf(v);
                if (MODE == 2 && col < 1024) v = (v > 0.f) ? v + 1.f : __expf(v);
                if (MODE == 0) ((float*)Cout)[(size_t)(row + r) * N + col] = v;
                else ((unsigned short*)Cout)[(size_t)(row + r) * N + col] = f2bf(v);
            }
        }
    }
}

// ---------------------------------------------------------------- kv partial: kv[c][d] += v[l,c]*k[l,d] over an L-chunk
__global__ __launch_bounds__(256)
void kv_partial(const unsigned short* __restrict__ Kb, const unsigned short* __restrict__ Vb,
                int ld, float* __restrict__ kvp, float* __restrict__ ksp)
{
    int chunk = blockIdx.x;   // 0..31 (128 rows each)
    int g = blockIdx.y;       // 0..15 = b*8+hkv
    int b = g >> 3, hkv = g & 7;
    __shared__ float kl[32][128];
    __shared__ float vl[32][128];
    int tid = threadIdx.x;
    int c0 = (tid >> 4) * 8, d0 = (tid & 15) * 8;
    float acc[8][8] = {};
    float ksacc = 0.0f;
    size_t rowBase = (size_t)b * SEQ + (size_t)chunk * 128;

    for (int sch = 0; sch < 4; ++sch) {
        __syncthreads();
        for (int t = tid; t < 512; t += 256) {
            int l = t >> 4, col = (t & 15) * 8;
            size_t off = (rowBase + sch * 32 + l) * ld + hkv * HD + col;
            uint4 kr = *(const uint4*)(Kb + off);
            uint4 vr = *(const uint4*)(Vb + off);
            unsigned int ku[4] = {kr.x, kr.y, kr.z, kr.w};
            unsigned int vu[4] = {vr.x, vr.y, vr.z, vr.w};
#pragma unroll
            for (int q = 0; q < 4; ++q) {
                kl[l][col + q * 2]     = bf2f((unsigned short)(ku[q] & 0xffff));
                kl[l][col + q * 2 + 1] = bf2f((unsigned short)(ku[q] >> 16));
                vl[l][col + q * 2]     = bf2f((unsigned short)(vu[q] & 0xffff));
                vl[l][col + q * 2 + 1] = bf2f((unsigned short)(vu[q] >> 16));
            }
        }
        __syncthreads();
        for (int l = 0; l < 32; ++l) {
            float vv[8], kk[8];
#pragma unroll
            for (int x = 0; x < 8; ++x) { vv[x] = vl[l][c0 + x]; kk[x] = kl[l][d0 + x]; }
#pragma unroll
            for (int x = 0; x < 8; ++x)
#pragma unroll
                for (int y = 0; y < 8; ++y)
                    acc[x][y] += vv[x] * kk[y];
        }
        if (tid < 128) {
            for (int l = 0; l < 32; ++l) ksacc += kl[l][tid];
        }
    }
    float* out = kvp + ((size_t)g * 32 + chunk) * (HD * HD);
#pragma unroll
    for (int x = 0; x < 8; ++x)
#pragma unroll
        for (int y = 0; y < 8; ++y)
            out[(c0 + x) * HD + d0 + y] = acc[x][y];
    if (tid < 128) ksp[((size_t)g * 32 + chunk) * HD + tid] = ksacc;
}

// ---------------------------------------------------------------- reduce partials -> kv_bf16, ksum
__global__ __launch_bounds__(256)
void kv_reduce(const float* __restrict__ kvp, const float* __restrict__ ksp,
               unsigned short* __restrict__ kvb, float* __restrict__ ksum)
{
    int slice = blockIdx.x;  // 0..15
    int g = blockIdx.y;      // 0..15
    int tid = threadIdx.x;
    int e = slice * 1024 + tid * 4;
    float4 s = {0.f, 0.f, 0.f, 0.f};
    for (int ch = 0; ch < 32; ++ch) {
        float4 p = *(const float4*)(kvp + ((size_t)g * 32 + ch) * (HD * HD) + e);
        s.x += p.x; s.y += p.y; s.z += p.z; s.w += p.w;
    }
    ushort4 o;
    o.x = f2bf(s.x); o.y = f2bf(s.y); o.z = f2bf(s.z); o.w = f2bf(s.w);
    *(ushort4*)(kvb + (size_t)g * HD * HD + e) = o;
    if (slice == 0 && tid < 128) {
        float ss = 0.f;
        for (int ch = 0; ch < 32; ++ch) ss += ksp[((size_t)g * 32 + ch) * HD + tid];
        ksum[g * HD + tid] = ss;
    }
}

// ---------------------------------------------------------------- attn GEMM: per (row-tile, head): C = q @ kv^T, /(ksum+eps), bf16 out
__global__ __launch_bounds__(256)
void attn_gemm(const unsigned short* __restrict__ Q,
               const unsigned short* __restrict__ KV,
               const float* __restrict__ KS,
               unsigned short* __restrict__ Out)
{
    const int BK = 32;
    __shared__ unsigned short As[128 * BK];
    __shared__ unsigned short Bs[128 * BK];

    int rt = blockIdx.x;   // 0..63
    int h  = blockIdx.y;   // 0..31
    int g = (rt >> 5) * NKV + (h >> 2);
    int rowBase = rt << 7;

    const unsigned short* A = Q + (size_t)h * HD;           // lda = HIDDEN
    const unsigned short* B = KV + (size_t)g * HD * HD;     // ldb = HD
    const float* ks = KS + g * HD;

    int tid = threadIdx.x;
    int wave = tid >> 6, lane = tid & 63;
    int wr = wave >> 1, wc = wave & 1;

    f32x4 acc[4][4] = {};

    int sr = lane >> 2;
    int sc = (lane & 3) * 8;

    const unsigned short* Aw = A + (size_t)(rowBase + wave * 32 + sr) * HIDDEN + sc;
    const unsigned short* Bw = B + (size_t)(wave * 32 + sr) * HD + sc;
    unsigned short* Asw = As + wave * 32 * BK;
    unsigned short* Bsw = Bs + wave * 32 * BK;

    int arow = (wr * 64 + (lane & 15)) * BK + (lane >> 4) * 8;
    int brow = (wc * 64 + (lane & 15)) * BK + (lane >> 4) * 8;

    for (int kt = 0; kt < HD; kt += BK) {
        gl2lds16(Aw + kt, Asw);
        gl2lds16(Aw + kt + (size_t)16 * HIDDEN, Asw + 16 * BK);
        gl2lds16(Bw + kt, Bsw);
        gl2lds16(Bw + kt + (size_t)16 * HD, Bsw + 16 * BK);
        __syncthreads();
        bf16x8 af[4], bfr[4];
#pragma unroll
        for (int i = 0; i < 4; ++i) af[i] = *(const bf16x8*)&As[arow + i * 16 * BK];
#pragma unroll
        for (int j = 0; j < 4; ++j) bfr[j] = *(const bf16x8*)&Bs[brow + j * 16 * BK];
#pragma unroll
        for (int i = 0; i < 4; ++i)
#pragma unroll
            for (int j = 0; j < 4; ++j)
                acc[i][j] = __builtin_amdgcn_mfma_f32_16x16x32_bf16(af[i], bfr[j], acc[i][j], 0, 0, 0);
        __syncthreads();
    }

    int r0 = rowBase + wr * 64 + ((lane >> 4) << 2);
    int c0 = wc * 64 + (lane & 15);
#pragma unroll
    for (int j = 0; j < 4; ++j) {
        int col = c0 + j * 16;
        float inv = 1.0f / (ks[col] + 1e-10f);
#pragma unroll
        for (int i = 0; i < 4; ++i) {
            int row = r0 + i * 16;
#pragma unroll
            for (int r = 0; r < 4; ++r) {
                float v = acc[i][j][r] * inv;
                Out[(size_t)(row + r) * HIDDEN + h * HD + col] = f2bf(v);
            }
        }
    }
}

// ---------------------------------------------------------------- launch
extern "C" void kernel_launch(void* const* d_in, const int* in_sizes, int n_in,
                              void* d_out, int out_size, void* d_ws, size_t ws_size,
                              hipStream_t stream)
{
    const float* hs = (const float*)d_in[0];
    const float* Wq = (const float*)d_in[1];
    const float* bq = (const float*)d_in[2];
    const float* Wk = (const float*)d_in[3];
    const float* bk = (const float*)d_in[4];
    const float* Wv = (const float*)d_in[5];
    const float* bv = (const float*)d_in[6];
    const float* Wo = (const float*)d_in[7];
    const float* bo = (const float*)d_in[8];

    char* ws = (char*)d_ws;
    size_t off = 0;
    auto alloc = [&](size_t bytes) -> char* {
        char* p = ws + off;
        off += (bytes + 255) & ~(size_t)255;
        return p;
    };

    unsigned short* hs_b  = (unsigned short*)alloc((size_t)ROWS * HIDDEN * 2);    // 67 MB (reused by attn out)
    unsigned short* Wq_b  = (unsigned short*)alloc((size_t)HIDDEN * HIDDEN * 2);  // 33.5 MB (reused by kvp)
    unsigned short* Wkv_b = (unsigned short*)alloc((size_t)2048 * HIDDEN * 2);    // 16.8 MB (Wk rows 0..1023, Wv rows 1024..2047)
    unsigned short* Wo_b  = (unsigned short*)alloc((size_t)HIDDEN * HIDDEN * 2);  // 33.5 MB
    unsigned short* kvout = (unsigned short*)alloc((size_t)ROWS * 2048 * 2);      // 33.5 MB [row][K(1024)|V(1024)]
    float* ksp   = (float*)alloc((size_t)16 * 32 * HD * 4);
    unsigned short* kvb = (unsigned short*)alloc((size_t)16 * HD * HD * 2);
    float* ksum  = (float*)alloc((size_t)16 * HD * 4);

    // aliases (lifetime-disjoint):
    float* kvp = (float*)Wq_b;                    // Wq dead after Q GEMM
    unsigned short* attn_b = hs_b;                // hs dead after KV GEMM
    unsigned short* q_b = (unsigned short*)d_out; // front 67 MB of d_out, dead before final GEMM writes

    (void)in_sizes; (void)n_in; (void)out_size; (void)ws_size;

    // fused cast: hs, Wq, Wk, Wv, Wo in ONE launch
    CastSegs cs;
    cs.in[0] = hs;  cs.out[0] = hs_b;                         cs.n4[0] = (ROWS * HIDDEN) / 4;
    cs.in[1] = Wq;  cs.out[1] = Wq_b;                         cs.n4[1] = (HIDDEN * HIDDEN) / 4;
    cs.in[2] = Wk;  cs.out[2] = Wkv_b;                        cs.n4[2] = (1024 * HIDDEN) / 4;
    cs.in[3] = Wv;  cs.out[3] = Wkv_b + (size_t)1024 * HIDDEN; cs.n4[3] = (1024 * HIDDEN) / 4;
    cs.in[4] = Wo;  cs.out[4] = Wo_b;                         cs.n4[4] = (HIDDEN * HIDDEN) / 4;
    cs.cum[0] = 0;
    for (int i = 1; i < 5; ++i) cs.cum[i] = cs.cum[i - 1] + cs.n4[i - 1];
    cs.total = cs.cum[4] + cs.n4[4];
    cast5_kernel<<<dim3(2048), dim3(256), 0, stream>>>(cs);

    // Q = phi(hs @ Wq^T + bq) -> bf16   [8192 x 4096], 512 wgs
    gemm256<1><<<dim3(512), dim3(512), 0, stream>>>(hs_b, HIDDEN, Wq_b, HIDDEN, bq, nullptr, q_b, ROWS, HIDDEN, HIDDEN);
    // [K|V] fused -> bf16  [8192 x 2048], 256 wgs
    gemm256<2><<<dim3(256), dim3(512), 0, stream>>>(hs_b, HIDDEN, Wkv_b, HIDDEN, bk, bv, kvout, ROWS, 2048, HIDDEN);

    // KV summary + ksum
    kv_partial<<<dim3(32, 16), dim3(256), 0, stream>>>(kvout, kvout + 1024, 2048, kvp, ksp);
    kv_reduce<<<dim3(16, 16), dim3(256), 0, stream>>>(kvp, ksp, kvb, ksum);

    // attn = (q @ kv^T) / (ksum + eps) -> bf16  [8192 x 4096]
    attn_gemm<<<dim3(64, 32), dim3(256), 0, stream>>>(q_b, kvb, ksum, attn_b);

    // out = attn @ Wo^T + bo -> f32
    gemm256<0><<<dim3(512), dim3(512), 0, stream>>>(attn_b, HIDDEN, Wo_b, HIDDEN, bo, nullptr, d_out, ROWS, HIDDEN, HIDDEN);
}